// Round 7
// baseline (89.406 us; speedup 1.0000x reference)
//
#include <hip/hip_runtime.h>

#define G_TOTAL 16384            // 128 x 128 grid
#define NPTS    8192             // context points
#define SPLIT   256              // p-chunks
#define P_CHUNK (NPTS / SPLIT)   // 32 points per block
#define KTILES  2                // k tiles of 64
#define KPB     64               // k rows per block
#define BLOCK   256
#define JT      8                // j per thread
#define KT      4                // k per thread  -> 96 accumulators

#define WS1_FLOATS (SPLIT * 3 * G_TOTAL)   // 50.3 MB partials
#define CG          8                      // chunk-groups in reduce1
#define CG_SIZE     (SPLIT / CG)           // 32 chunks per group

// Raw v_exp_f32 — args in [-40, 0]: no fixup needed.
__device__ __forceinline__ float fast_exp2(float x) {
#if __has_builtin(__builtin_amdgcn_exp2f)
    return __builtin_amdgcn_exp2f(x);
#else
    float r; asm("v_exp_f32 %0, %1" : "=v"(r) : "v"(x)); return r;
#endif
}

// ---------------------------------------------------------------------------
// R7: separable Gaussian, rescheduled. R6's algorithm was right but ran at
// 1 wave/SIMD (113 KB LDS -> 1 block/CU). Here: 40.5 KB LDS, 512 blocks of
// 256 thr -> 2 blocks/CU, 8 waves/CU. Thread tile 8j x 4k x 3c = 96 acc;
// inner loop per p: 5 ds_read_b128 (0.83 B/FMA) + 96 fma.
// Floors: FMA 5.1us, DS 6.4us device-wide.
//   grid: blockIdx.x = chunk*2 + ktile
//   Ex[p][j] = exp2(-(s*gx_j - s*px_p)^2)   (16 KB)
//   B[p][k*3+c] = Ey[p][k] * {1, y0, y1}    (24 KB, 12 floats/thread = 3 b128)
// Partials -> ws[chunk][c][g]; reduced by 2-stage tree (deterministic).
// ---------------------------------------------------------------------------
__global__ __launch_bounds__(BLOCK) void enc_phase2(
    const float* __restrict__ X,   // (8192, 2)
    const float* __restrict__ Y,   // (8192, 2)
    float* __restrict__ ws)
{
    __shared__ float4 sPts[P_CHUNK];            // {s*px, s*py, y0, y1}
    __shared__ float  sEx[P_CHUNK][128];        // 16 KB
    __shared__ float  sB [P_CHUNK][KPB * 3];    // 24 KB

    const int t     = threadIdx.x;
    const int ktile = blockIdx.x & 1;
    const int chunk = blockIdx.x >> 1;
    const int kBase = ktile * KPB;
    const int pBase = chunk * P_CHUNK;

    const float s    = 0.84932184f;             // sqrt(0.5 * log2(e))
    const float step = 4.0f / 127.0f;

    // ---- stage the 32 context points
    if (t < P_CHUNK) {
        float2 xv = ((const float2*)X)[pBase + t];
        float2 yv = ((const float2*)Y)[pBase + t];
        sPts[t] = make_float4(xv.x * s, xv.y * s, yv.x, yv.y);
    }
    __syncthreads();

    // ---- Ex table: 32p x 128j, 16 exps/thread (p wave-uniform -> broadcast)
    {
        const int j  = t & 127;
        const int ph = t >> 7;
        const float gxs = (-2.0f + step * (float)j) * s;
#pragma unroll
        for (int i = 0; i < 16; ++i) {
            const int p = ph * 16 + i;
            float dx = gxs - sPts[p].x;
            sEx[p][j] = fast_exp2(-dx * dx);
        }
    }
    // ---- B table: 32p x 64k x 3c, 8 exps/thread (p wave-uniform)
    {
        const int k  = t & 63;
        const int pq = t >> 6;
        const float gys = (2.0f - step * (float)(kBase + k)) * s;
#pragma unroll
        for (int i = 0; i < 8; ++i) {
            const int p = pq * 8 + i;
            float4 pt = sPts[p];
            float dy = gys - pt.y;
            float ey = fast_exp2(-dy * dy);
            sB[p][k * 3 + 0] = ey;
            sB[p][k * 3 + 1] = ey * pt.z;
            sB[p][k * 3 + 2] = ey * pt.w;
        }
    }
    __syncthreads();

    // ---- main loop: 32 p x (5 ds_read_b128 + 96 fma)
    const int jg = t & 15;          // 16 x 8j = 128
    const int kg = t >> 4;          // 16 x 4k = 64
    const int j0 = jg * 8;
    const int k0 = kg * 4;

    float acc[KT][3][JT];
#pragma unroll
    for (int k = 0; k < KT; ++k)
#pragma unroll
        for (int c = 0; c < 3; ++c)
#pragma unroll
            for (int j = 0; j < JT; ++j) acc[k][c][j] = 0.0f;

#pragma unroll 2
    for (int p = 0; p < P_CHUNK; ++p) {
        float4 exA = *(const float4*)&sEx[p][j0];       // 32B-aligned
        float4 exB = *(const float4*)&sEx[p][j0 + 4];
        const float* bp = &sB[p][k0 * 3];               // 48*kg B, 16-aligned
        float4 b0 = *(const float4*)(bp);
        float4 b1 = *(const float4*)(bp + 4);
        float4 b2 = *(const float4*)(bp + 8);
        const float ex[JT] = {exA.x, exA.y, exA.z, exA.w,
                              exB.x, exB.y, exB.z, exB.w};
        const float bv[KT][3] = {{b0.x, b0.y, b0.z}, {b0.w, b1.x, b1.y},
                                 {b1.z, b1.w, b2.x}, {b2.y, b2.z, b2.w}};
#pragma unroll
        for (int k = 0; k < KT; ++k)
#pragma unroll
            for (int c = 0; c < 3; ++c)
#pragma unroll
                for (int j = 0; j < JT; ++j)
                    acc[k][c][j] = fmaf(ex[j], bv[k][c], acc[k][c][j]);
    }

    // ---- write partials: ws[chunk][c][g], 2 x b128 per (k,c)
#pragma unroll
    for (int k = 0; k < KT; ++k) {
        const int g = (kBase + k0 + k) * 128 + j0;
#pragma unroll
        for (int c = 0; c < 3; ++c) {
            float* w = ws + (size_t)(chunk * 3 + c) * G_TOTAL + g;
            *(float4*)&w[0] = make_float4(acc[k][c][0], acc[k][c][1],
                                          acc[k][c][2], acc[k][c][3]);
            *(float4*)&w[4] = make_float4(acc[k][c][4], acc[k][c][5],
                                          acc[k][c][6], acc[k][c][7]);
        }
    }
}

// ---------------------------------------------------------------------------
// Reduce stage 1: 512 blocks, each sums 32 chunks for a 256-g slice.
// Deterministic (no atomics). Output: ws2[cg][c][g] after the partials.
// ---------------------------------------------------------------------------
__global__ __launch_bounds__(256) void reduce1_kernel(
    const float* __restrict__ ws, float* __restrict__ ws2)
{
    const int cg = blockIdx.x >> 6;          // 8 chunk-groups
    const int gs = blockIdx.x & 63;          // 64 g-slices
    const int g  = gs * 256 + threadIdx.x;

#pragma unroll
    for (int c = 0; c < 3; ++c) {
        float sum = 0.0f;
#pragma unroll 8
        for (int i = 0; i < CG_SIZE; ++i) {
            const int chunk = cg * CG_SIZE + i;
            sum += ws[(size_t)(chunk * 3 + c) * G_TOTAL + g];
        }
        ws2[(size_t)(cg * 3 + c) * G_TOTAL + g] = sum;
    }
}

// ---------------------------------------------------------------------------
// Reduce stage 2: sum the 8 group-partials, normalize, write final output.
// ---------------------------------------------------------------------------
__global__ __launch_bounds__(256) void reduce2_kernel(
    const float* __restrict__ ws2, float* __restrict__ out)
{
    const int g = blockIdx.x * 256 + threadIdx.x;
    float c0 = 0.0f, c1 = 0.0f, c2 = 0.0f;
#pragma unroll
    for (int cg = 0; cg < CG; ++cg) {
        const float* w = ws2 + (size_t)(cg * 3) * G_TOTAL;
        c0 += w[g];
        c1 += w[G_TOTAL + g];
        c2 += w[2 * G_TOTAL + g];
    }
    float inv = 1.0f / c0;
    out[g]               = c0;
    out[G_TOTAL + g]     = c1 * inv;
    out[2 * G_TOTAL + g] = c2 * inv;
}

// ---------------------------------------------------------------------------
extern "C" void kernel_launch(void* const* d_in, const int* in_sizes, int n_in,
                              void* d_out, int out_size, void* d_ws, size_t ws_size,
                              hipStream_t stream) {
    const float* X = (const float*)d_in[0];
    const float* Y = (const float*)d_in[1];
    float* out = (float*)d_out;
    float* ws  = (float*)d_ws;                 // 50.3 MB + 1.6 MB used
    float* ws2 = ws + WS1_FLOATS;

    enc_phase2<<<SPLIT * KTILES, BLOCK, 0, stream>>>(X, Y, ws);
    reduce1_kernel<<<512, 256, 0, stream>>>(ws, ws2);
    reduce2_kernel<<<G_TOTAL / 256, 256, 0, stream>>>(ws2, out);
}

// Round 8
// 82.971 us; speedup vs baseline: 1.0776x; 1.0776x over previous
//
#include <hip/hip_runtime.h>

#define G_TOTAL 16384            // 128 x 128 grid
#define NPTS    8192             // context points
#define SPLIT   256              // p-chunks
#define P_CHUNK (NPTS / SPLIT)   // 32 points per block
#define KTILES  2                // k tiles of 64
#define KPB     64               // k rows per block
#define BLOCK   256
#define JT      8                // j per thread
#define KT      4                // k per thread  -> 96 accumulators

typedef _Float16 half8 __attribute__((ext_vector_type(8)));

// Raw v_exp_f32 — args in [-40, 0]: no fixup needed.
__device__ __forceinline__ float fast_exp2(float x) {
#if __has_builtin(__builtin_amdgcn_exp2f)
    return __builtin_amdgcn_exp2f(x);
#else
    float r; asm("v_exp_f32 %0, %1" : "=v"(r) : "v"(x)); return r;
#endif
}

// ---------------------------------------------------------------------------
// R8: R7's verified enc (separable Gaussian, 512 blocks, 2/CU, 8 waves/CU,
// absmax 3e-5) with fp16 partials (ws 50->24.6 MB: halves the harness-fill
// dirty-writeback penalty, which R7 showed costs ~1.4 us per 10 MB of ws
// footprint) and a single fused reduce+normalize kernel (3 -> 2 dispatches).
//   Ex[p][j] = exp2(-(s*gx_j - s*px_p)^2)   (16 KB LDS)
//   B[p][k*3+c] = Ey[p][k] * {1, y0, y1}    (24 KB LDS)
//   inner loop per p: 5 ds_read_b128 + 96 fma (floors: FMA 5.1us, DS 6.4us)
// ---------------------------------------------------------------------------
__global__ __launch_bounds__(BLOCK) void enc_phase2(
    const float* __restrict__ X,   // (8192, 2)
    const float* __restrict__ Y,   // (8192, 2)
    _Float16* __restrict__ ws)     // (SPLIT, 3, 16384) fp16 partials
{
    __shared__ float4 sPts[P_CHUNK];            // {s*px, s*py, y0, y1}
    __shared__ float  sEx[P_CHUNK][128];        // 16 KB
    __shared__ float  sB [P_CHUNK][KPB * 3];    // 24 KB

    const int t     = threadIdx.x;
    const int ktile = blockIdx.x & 1;
    const int chunk = blockIdx.x >> 1;
    const int kBase = ktile * KPB;
    const int pBase = chunk * P_CHUNK;

    const float s    = 0.84932184f;             // sqrt(0.5 * log2(e))
    const float step = 4.0f / 127.0f;

    if (t < P_CHUNK) {
        float2 xv = ((const float2*)X)[pBase + t];
        float2 yv = ((const float2*)Y)[pBase + t];
        sPts[t] = make_float4(xv.x * s, xv.y * s, yv.x, yv.y);
    }
    __syncthreads();

    // ---- Ex table: 32p x 128j, 16 exps/thread
    {
        const int j  = t & 127;
        const int ph = t >> 7;
        const float gxs = (-2.0f + step * (float)j) * s;
#pragma unroll
        for (int i = 0; i < 16; ++i) {
            const int p = ph * 16 + i;
            float dx = gxs - sPts[p].x;
            sEx[p][j] = fast_exp2(-dx * dx);
        }
    }
    // ---- B table: 32p x 64k x 3c, 8 exps/thread
    {
        const int k  = t & 63;
        const int pq = t >> 6;
        const float gys = (2.0f - step * (float)(kBase + k)) * s;
#pragma unroll
        for (int i = 0; i < 8; ++i) {
            const int p = pq * 8 + i;
            float4 pt = sPts[p];
            float dy = gys - pt.y;
            float ey = fast_exp2(-dy * dy);
            sB[p][k * 3 + 0] = ey;
            sB[p][k * 3 + 1] = ey * pt.z;
            sB[p][k * 3 + 2] = ey * pt.w;
        }
    }
    __syncthreads();

    // ---- main loop: 32 p x (5 ds_read_b128 + 96 fma)
    const int jg = t & 15;
    const int kg = t >> 4;
    const int j0 = jg * 8;
    const int k0 = kg * 4;

    float acc[KT][3][JT];
#pragma unroll
    for (int k = 0; k < KT; ++k)
#pragma unroll
        for (int c = 0; c < 3; ++c)
#pragma unroll
            for (int j = 0; j < JT; ++j) acc[k][c][j] = 0.0f;

#pragma unroll 2
    for (int p = 0; p < P_CHUNK; ++p) {
        float4 exA = *(const float4*)&sEx[p][j0];
        float4 exB = *(const float4*)&sEx[p][j0 + 4];
        const float* bp = &sB[p][k0 * 3];
        float4 b0 = *(const float4*)(bp);
        float4 b1 = *(const float4*)(bp + 4);
        float4 b2 = *(const float4*)(bp + 8);
        const float ex[JT] = {exA.x, exA.y, exA.z, exA.w,
                              exB.x, exB.y, exB.z, exB.w};
        const float bv[KT][3] = {{b0.x, b0.y, b0.z}, {b0.w, b1.x, b1.y},
                                 {b1.z, b1.w, b2.x}, {b2.y, b2.z, b2.w}};
#pragma unroll
        for (int k = 0; k < KT; ++k)
#pragma unroll
            for (int c = 0; c < 3; ++c)
#pragma unroll
                for (int j = 0; j < JT; ++j)
                    acc[k][c][j] = fmaf(ex[j], bv[k][c], acc[k][c][j]);
    }

    // ---- write fp16 partials: one half8 (16 B) per (k,c)
#pragma unroll
    for (int k = 0; k < KT; ++k) {
        const int g = (kBase + k0 + k) * 128 + j0;   // j0 % 8 == 0 -> 16B aligned
#pragma unroll
        for (int c = 0; c < 3; ++c) {
            half8 h;
#pragma unroll
            for (int j = 0; j < JT; ++j) h[j] = (_Float16)acc[k][c][j];
            *(half8*)(ws + (size_t)(chunk * 3 + c) * G_TOTAL + g) = h;
        }
    }
}

// ---------------------------------------------------------------------------
// Fused reduce + normalize: 256 blocks x 256 thr. Each block owns 64 grid
// points; 4 thread-quarters each sum 64 chunks (coalesced: 64 lanes x 2B =
// one 128B line per load), LDS tree 4->1, then normalize and store.
// ---------------------------------------------------------------------------
__global__ __launch_bounds__(256) void reduce_norm(
    const _Float16* __restrict__ ws, float* __restrict__ out)
{
    __shared__ float red[4][3][64];   // 3 KB

    const int t  = threadIdx.x;
    const int gl = t & 63;
    const int q  = t >> 6;
    const int g  = blockIdx.x * 64 + gl;

    float c0 = 0.0f, c1 = 0.0f, c2 = 0.0f;
#pragma unroll 4
    for (int i = 0; i < SPLIT / 4; ++i) {
        const int chunk = q * (SPLIT / 4) + i;
        const _Float16* w = ws + (size_t)(chunk * 3) * G_TOTAL + g;
        c0 += (float)w[0];
        c1 += (float)w[G_TOTAL];
        c2 += (float)w[2 * G_TOTAL];
    }
    red[q][0][gl] = c0;
    red[q][1][gl] = c1;
    red[q][2][gl] = c2;
    __syncthreads();

    if (t < 64) {
        float s0 = red[0][0][t] + red[1][0][t] + red[2][0][t] + red[3][0][t];
        float s1 = red[0][1][t] + red[1][1][t] + red[2][1][t] + red[3][1][t];
        float s2 = red[0][2][t] + red[1][2][t] + red[2][2][t] + red[3][2][t];
        float inv = 1.0f / s0;
        const int go = blockIdx.x * 64 + t;
        out[go]               = s0;
        out[G_TOTAL + go]     = s1 * inv;
        out[2 * G_TOTAL + go] = s2 * inv;
    }
}

// ---------------------------------------------------------------------------
extern "C" void kernel_launch(void* const* d_in, const int* in_sizes, int n_in,
                              void* d_out, int out_size, void* d_ws, size_t ws_size,
                              hipStream_t stream) {
    const float* X = (const float*)d_in[0];
    const float* Y = (const float*)d_in[1];
    float* out = (float*)d_out;
    _Float16* ws = (_Float16*)d_ws;           // 24.6 MB used

    enc_phase2<<<SPLIT * KTILES, BLOCK, 0, stream>>>(X, Y, ws);
    reduce_norm<<<G_TOTAL / 64, BLOCK, 0, stream>>>(ws, out);
}